// Round 4
// baseline (437.279 us; speedup 1.0000x reference)
//
#include <hip/hip_runtime.h>
#include <math.h>

#define N 8192
#define NV4 (N / 4)             // float4 columns per row
#define THREADS 256

// Pass-1 strips (colsum): streaming is occupancy-insensitive, keep partials small.
#define RPB1 64
#define NBY1 (N / RPB1)         // 128 strips
// Pass-2 strips (matvec): 32 rows -> 2048 blocks -> 32 waves/CU (latency hiding).
#define RPB2 32
#define NBY2 (N / RPB2)         // 256 strips
#define GRID_X 8                // NV4 / THREADS

typedef float f4 __attribute__((ext_vector_type(4)));

// ws layout (floats) — every region fully overwritten before read (poison-safe),
// no atomics. Cached (non-NT) stores throughout: consumers read L2/L3.
//   degp  : [NBY1][N]     pass-1 partial column sums             (4 MB)
//   tpart : [NBY2][2][N]  pass-2 partial matvec results          (16 MB)
//   dinvg : [N]           rsqrt(deg)
//   g0,g1 : [N]           dinv[r] * x[b][r] per batch
//   hpart : [2][32]       per-(batch, head-block) partial sums of h3
#define DEGP_OFF  0
#define TPART_OFF (NBY1 * N)
#define DINV_OFF  (TPART_OFF + NBY2 * 2 * N)
#define G0_OFF    (DINV_OFF + N)
#define G1_OFF    (G0_OFF + N)
#define HPART_OFF (G1_OFF + N)

// Pass 1: per-strip partial column sums (DSM streamed HBM->L3, read once).
__global__ void k_colsum(const float* __restrict__ dsm, float* __restrict__ degp) {
    int chunk = (blockIdx.x + blockIdx.y) & (GRID_X - 1);   // column-phase swizzle
    int c4 = chunk * THREADS + threadIdx.x;
    int r0 = blockIdx.y * RPB1;
    const f4* p = (const f4*)dsm + (size_t)r0 * NV4 + c4;
    f4 acc = 0.f;
#pragma unroll 8
    for (int i = 0; i < RPB1; ++i) acc += p[(size_t)i * NV4];
    ((f4*)(degp + (size_t)blockIdx.y * N))[c4] = acc;
}

// Tiny: full deg reduction + dinv + pre-scaled per-row gather weights.
// 256 blocks x 256 threads; block owns 32 columns, 8-way strip split.
__global__ void k_dinv(const float* __restrict__ degp, const float* __restrict__ x,
                       float* __restrict__ dinvg, float* __restrict__ g0,
                       float* __restrict__ g1) {
    __shared__ float sred[8][32];
    int c0 = blockIdx.x * 32;
    int cl = threadIdx.x & 31;
    int q  = threadIdx.x >> 5;
    const float* dp = degp + c0 + cl;
    float s = 0.f;
#pragma unroll 8
    for (int j = 0; j < NBY1 / 8; ++j) s += dp[(size_t)(q * (NBY1 / 8) + j) * N];
    sred[q][cl] = s;
    __syncthreads();
    if (threadIdx.x < 32) {
        int c = c0 + threadIdx.x;
        float d = 0.f;
#pragma unroll
        for (int q2 = 0; q2 < 8; ++q2) d += sred[q2][threadIdx.x];
        float di = d > 0.f ? rsqrtf(d) : 0.f;
        dinvg[c] = di;
        g0[c] = di * x[c];
        g1[c] = di * x[N + c];
    }
}

// Pass 2: weighted partial matvec over a 32-row strip. 2048 blocks -> 32
// waves/CU for L3-latency hiding (VGPR<=64 keeps 8 waves/SIMD). DSM reads are
// L3 hits (256 MiB streamed in by pass 1).
__global__ void k_matvec(const float* __restrict__ dsm, const float* __restrict__ g0,
                         const float* __restrict__ g1, float* __restrict__ tpart) {
    __shared__ float sg0[RPB2];
    __shared__ float sg1[RPB2];
    int r0 = blockIdx.y * RPB2;
    if (threadIdx.x < RPB2) {
        sg0[threadIdx.x] = g0[r0 + threadIdx.x];
        sg1[threadIdx.x] = g1[r0 + threadIdx.x];
    }
    __syncthreads();
    int chunk = (blockIdx.x + blockIdx.y) & (GRID_X - 1);
    int c4 = chunk * THREADS + threadIdx.x;
    const f4* p = (const f4*)dsm + (size_t)r0 * NV4 + c4;
    f4 a0 = 0.f, a1 = 0.f;
#pragma unroll 8
    for (int i = 0; i < RPB2; ++i) {
        f4 v = p[(size_t)i * NV4];
        a0 += v * sg0[i];
        a1 += v * sg1[i];
    }
    ((f4*)(tpart + ((size_t)blockIdx.y * 2 + 0) * N))[c4] = a0;
    ((f4*)(tpart + ((size_t)blockIdx.y * 2 + 1) * N))[c4] = a1;
}

// Head: grid (32, 2), 1024 threads. 4 threads per column split the 256-strip
// tpart reduction (64 strided L3 loads each), LDS combine, then the scalar MLP
// chain + block reduction of h3.
__global__ void k_head(const float* __restrict__ dinvg, const float* __restrict__ tpart,
                       const float* __restrict__ w1, const float* __restrict__ b1,
                       const float* __restrict__ lw1, const float* __restrict__ lb1,
                       const float* __restrict__ lw2, const float* __restrict__ lb2,
                       float* __restrict__ hpart, float* __restrict__ out) {
    __shared__ float sred[4][256];
    __shared__ float swred[4];
    int cl = threadIdx.x & 255;          // column within block
    int q  = threadIdx.x >> 8;           // quarter: 64 strips each
    int c  = blockIdx.x * 256 + cl;
    int b  = blockIdx.y;

    const float* tp = tpart + (size_t)b * N + c + (size_t)(q * 64) * 2 * N;
    float t = 0.f;
#pragma unroll 8
    for (int by = 0; by < 64; ++by) t += tp[(size_t)by * 2 * N];
    sred[q][cl] = t;
    __syncthreads();

    if (threadIdx.x < 256) {
        float tt = sred[0][cl] + sred[1][cl] + sred[2][cl] + sred[3][cl];
        float di = dinvg[c];
        float h = fmaxf(w1[0] * di * tt + b1[0], 0.f);
        h = fmaxf(h * lw1[0] + lb1[0], 0.f);
        h = fmaxf(h * lw2[0] + lb2[0], 0.f);

        // softmax over singleton last axis == 1.0 exactly
        out[(size_t)b * N + c] = 1.0f;

        // reduce h across the 256 finalizer threads (4 waves)
        float v = h;
        for (int off = 32; off > 0; off >>= 1) v += __shfl_down(v, off);
        int wave = threadIdx.x >> 6;
        if ((threadIdx.x & 63) == 0) swred[wave] = v;
    }
    __syncthreads();
    if (threadIdx.x == 0)
        hpart[b * 32 + blockIdx.x] = swred[0] + swred[1] + swred[2] + swred[3];
}

__global__ void k_out(const float* __restrict__ hpart,
                      const float* __restrict__ w2, const float* __restrict__ b2,
                      const float* __restrict__ w3, const float* __restrict__ b3,
                      const float* __restrict__ wv, const float* __restrict__ bv,
                      float* __restrict__ out) {
    int tid = threadIdx.x;
    float s0 = tid < 32 ? hpart[tid] : 0.f;
    float s1 = tid < 32 ? hpart[32 + tid] : 0.f;
    for (int off = 16; off > 0; off >>= 1) {
        s0 += __shfl_down(s0, off);
        s1 += __shfl_down(s1, off);
    }
    if (tid == 0) {
        float m0 = s0 * (1.0f / (float)N);
        float m1 = s1 * (1.0f / (float)N);
        float a = fmaxf(m0 * w2[0] + b2[0], 0.f);
        a = fmaxf(a * w3[0] + b3[0], 0.f);
        float b = fmaxf(m1 * w2[0] + b2[0], 0.f);
        b = fmaxf(b * w3[0] + b3[0], 0.f);
        float vmax = fmaxf(a, b);
        out[2 * N] = vmax * wv[0] + bv[0];
    }
}

extern "C" void kernel_launch(void* const* d_in, const int* in_sizes, int n_in,
                              void* d_out, int out_size, void* d_ws, size_t ws_size,
                              hipStream_t stream) {
    const float* x   = (const float*)d_in[0];
    const float* dsm = (const float*)d_in[1];
    const float* w1  = (const float*)d_in[2];
    const float* b1  = (const float*)d_in[3];
    const float* lw1 = (const float*)d_in[4];
    const float* lb1 = (const float*)d_in[5];
    const float* lw2 = (const float*)d_in[6];
    const float* lb2 = (const float*)d_in[7];
    const float* w2  = (const float*)d_in[8];
    const float* b2  = (const float*)d_in[9];
    const float* w3  = (const float*)d_in[10];
    const float* b3  = (const float*)d_in[11];
    // d_in[12..13] = wa, ba unused: softmax over a singleton axis == 1.0
    const float* wv  = (const float*)d_in[14];
    const float* bv  = (const float*)d_in[15];

    float* ws    = (float*)d_ws;
    float* degp  = ws + DEGP_OFF;
    float* tpart = ws + TPART_OFF;
    float* dinvg = ws + DINV_OFF;
    float* g0    = ws + G0_OFF;
    float* g1    = ws + G1_OFF;
    float* hpart = ws + HPART_OFF;

    k_colsum<<<dim3(GRID_X, NBY1), THREADS, 0, stream>>>(dsm, degp);
    k_dinv<<<N / 32, THREADS, 0, stream>>>(degp, x, dinvg, g0, g1);
    k_matvec<<<dim3(GRID_X, NBY2), THREADS, 0, stream>>>(dsm, g0, g1, tpart);
    k_head<<<dim3(N / 256, 2), 1024, 0, stream>>>(dinvg, tpart, w1, b1,
                                                  lw1, lb1, lw2, lb2,
                                                  hpart, (float*)d_out);
    k_out<<<1, 64, 0, stream>>>(hpart, w2, b2, w3, b3, wv, bv, (float*)d_out);
}

// Round 6
// 431.665 us; speedup vs baseline: 1.0130x; 1.0130x over previous
//
#include <hip/hip_runtime.h>
#include <math.h>

#define N 8192
#define NV4 (N / 4)             // float4 columns per row
#define THREADS 256
#define RPB 64                  // rows per strip (both passes)
#define NBY (N / RPB)           // 128 strips
#define GRID_X 8                // NV4 / THREADS

typedef float f4 __attribute__((ext_vector_type(4)));

// ws layout (floats) — every region fully overwritten before read (poison-safe),
// no atomics anywhere (replay-safe for rocprof counter groups).
// Cached (non-NT) stores throughout: consumers read L2/L3 (NT regressed R2).
//   degp  : [NBY][N]      pass-1 partial column sums             (4 MB)
//   tpart : [NBY][2][N]   pass-2 partial matvec results          (8 MB)
//   dinvg : [N]           rsqrt(deg)
//   g0,g1 : [N]           dinv[r] * x[b][r] per batch
//   hpart : [2][32]       per-(batch, head-block) partial sums of h3
#define DEGP_OFF  0
#define TPART_OFF (NBY * N)
#define DINV_OFF  (TPART_OFF + NBY * 2 * N)
#define G0_OFF    (DINV_OFF + N)
#define G1_OFF    (G0_OFF + N)
#define HPART_OFF (G1_OFF + N)

// Pass 1: per-strip partial column sums (DSM streamed HBM->L3, read once).
__global__ void k_colsum(const float* __restrict__ dsm, float* __restrict__ degp) {
    int chunk = (blockIdx.x + blockIdx.y) & (GRID_X - 1);   // column-phase swizzle
    int c4 = chunk * THREADS + threadIdx.x;
    int r0 = blockIdx.y * RPB;
    const f4* p = (const f4*)dsm + (size_t)r0 * NV4 + c4;
    f4 acc = 0.f;
#pragma unroll 8
    for (int i = 0; i < RPB; ++i) acc += p[(size_t)i * NV4];
    ((f4*)(degp + (size_t)blockIdx.y * N))[c4] = acc;
}

// Tiny: full deg reduction + dinv + pre-scaled per-row gather weights.
// 256 blocks x 256 threads; block owns 32 columns, 8-way strip split.
__global__ void k_dinv(const float* __restrict__ degp, const float* __restrict__ x,
                       float* __restrict__ dinvg, float* __restrict__ g0,
                       float* __restrict__ g1) {
    __shared__ float sred[8][32];
    int c0 = blockIdx.x * 32;
    int cl = threadIdx.x & 31;
    int q  = threadIdx.x >> 5;
    const float* dp = degp + c0 + cl;
    float s = 0.f;
#pragma unroll 8
    for (int j = 0; j < NBY / 8; ++j) s += dp[(size_t)(q * (NBY / 8) + j) * N];
    sred[q][cl] = s;
    __syncthreads();
    if (threadIdx.x < 32) {
        int c = c0 + threadIdx.x;
        float d = 0.f;
#pragma unroll
        for (int q2 = 0; q2 < 8; ++q2) d += sred[q2][threadIdx.x];
        float di = d > 0.f ? rsqrtf(d) : 0.f;
        dinvg[c] = di;
        g0[c] = di * x[c];
        g1[c] = di * x[N + c];
    }
}

// Pass 2: weighted partial matvec over a 64-row strip. Strip order REVERSED
// vs pass 1: first-dispatched blocks touch the freshest (still L2-resident)
// lines pass 1 wrote last.
__global__ void k_matvec(const float* __restrict__ dsm, const float* __restrict__ g0,
                         const float* __restrict__ g1, float* __restrict__ tpart) {
    __shared__ float sg0[RPB];
    __shared__ float sg1[RPB];
    int by = NBY - 1 - blockIdx.y;           // reversed strip order
    int r0 = by * RPB;
    if (threadIdx.x < RPB) {
        sg0[threadIdx.x] = g0[r0 + threadIdx.x];
        sg1[threadIdx.x] = g1[r0 + threadIdx.x];
    }
    __syncthreads();
    int chunk = (blockIdx.x + blockIdx.y) & (GRID_X - 1);
    int c4 = chunk * THREADS + threadIdx.x;
    const f4* p = (const f4*)dsm + (size_t)r0 * NV4 + c4;
    f4 a0 = 0.f, a1 = 0.f;
#pragma unroll 8
    for (int i = 0; i < RPB; ++i) {
        f4 v = p[(size_t)i * NV4];
        a0 += v * sg0[i];
        a1 += v * sg1[i];
    }
    ((f4*)(tpart + ((size_t)by * 2 + 0) * N))[c4] = a0;
    ((f4*)(tpart + ((size_t)by * 2 + 1) * N))[c4] = a1;
}

// Head: grid (32, 2), 1024 threads. 4 threads/column split the 128-strip
// tpart reduction (32 strided L3 loads each), LDS combine, scalar MLP chain,
// block-reduce h3 into hpart.
__global__ void k_head(const float* __restrict__ dinvg, const float* __restrict__ tpart,
                       const float* __restrict__ w1, const float* __restrict__ b1,
                       const float* __restrict__ lw1, const float* __restrict__ lb1,
                       const float* __restrict__ lw2, const float* __restrict__ lb2,
                       float* __restrict__ hpart, float* __restrict__ out) {
    __shared__ float sred[4][256];
    __shared__ float swred[4];
    int cl = threadIdx.x & 255;          // column within block
    int q  = threadIdx.x >> 8;           // quarter: 32 strips each
    int c  = blockIdx.x * 256 + cl;
    int b  = blockIdx.y;

    const float* tp = tpart + (size_t)b * N + c + (size_t)(q * 32) * 2 * N;
    float t = 0.f;
#pragma unroll 8
    for (int by = 0; by < 32; ++by) t += tp[(size_t)by * 2 * N];
    sred[q][cl] = t;
    __syncthreads();

    if (threadIdx.x < 256) {
        float tt = sred[0][cl] + sred[1][cl] + sred[2][cl] + sred[3][cl];
        float di = dinvg[c];
        float h = fmaxf(w1[0] * di * tt + b1[0], 0.f);
        h = fmaxf(h * lw1[0] + lb1[0], 0.f);
        h = fmaxf(h * lw2[0] + lb2[0], 0.f);

        // softmax over singleton last axis == 1.0 exactly
        out[(size_t)b * N + c] = 1.0f;

        // reduce h across the 256 finalizer threads (4 full waves)
        float v = h;
        for (int off = 32; off > 0; off >>= 1) v += __shfl_down(v, off);
        int wave = threadIdx.x >> 6;
        if ((threadIdx.x & 63) == 0) swred[wave] = v;
    }
    __syncthreads();
    if (threadIdx.x == 0)
        hpart[b * 32 + blockIdx.x] = swred[0] + swred[1] + swred[2] + swred[3];
}

__global__ void k_out(const float* __restrict__ hpart,
                      const float* __restrict__ w2, const float* __restrict__ b2,
                      const float* __restrict__ w3, const float* __restrict__ b3,
                      const float* __restrict__ wv, const float* __restrict__ bv,
                      float* __restrict__ out) {
    int tid = threadIdx.x;
    float s0 = tid < 32 ? hpart[tid] : 0.f;
    float s1 = tid < 32 ? hpart[32 + tid] : 0.f;
    for (int off = 16; off > 0; off >>= 1) {
        s0 += __shfl_down(s0, off);
        s1 += __shfl_down(s1, off);
    }
    if (tid == 0) {
        float m0 = s0 * (1.0f / (float)N);
        float m1 = s1 * (1.0f / (float)N);
        float a = fmaxf(m0 * w2[0] + b2[0], 0.f);
        a = fmaxf(a * w3[0] + b3[0], 0.f);
        float b = fmaxf(m1 * w2[0] + b2[0], 0.f);
        b = fmaxf(b * w3[0] + b3[0], 0.f);
        float vmax = fmaxf(a, b);
        out[2 * N] = vmax * wv[0] + bv[0];
    }
}

extern "C" void kernel_launch(void* const* d_in, const int* in_sizes, int n_in,
                              void* d_out, int out_size, void* d_ws, size_t ws_size,
                              hipStream_t stream) {
    const float* x   = (const float*)d_in[0];
    const float* dsm = (const float*)d_in[1];
    const float* w1  = (const float*)d_in[2];
    const float* b1  = (const float*)d_in[3];
    const float* lw1 = (const float*)d_in[4];
    const float* lb1 = (const float*)d_in[5];
    const float* lw2 = (const float*)d_in[6];
    const float* lb2 = (const float*)d_in[7];
    const float* w2  = (const float*)d_in[8];
    const float* b2  = (const float*)d_in[9];
    const float* w3  = (const float*)d_in[10];
    const float* b3  = (const float*)d_in[11];
    // d_in[12..13] = wa, ba unused: softmax over a singleton axis == 1.0
    const float* wv  = (const float*)d_in[14];
    const float* bv  = (const float*)d_in[15];

    float* ws    = (float*)d_ws;
    float* degp  = ws + DEGP_OFF;
    float* tpart = ws + TPART_OFF;
    float* dinvg = ws + DINV_OFF;
    float* g0    = ws + G0_OFF;
    float* g1    = ws + G1_OFF;
    float* hpart = ws + HPART_OFF;

    k_colsum<<<dim3(GRID_X, NBY), THREADS, 0, stream>>>(dsm, degp);
    k_dinv<<<N / 32, THREADS, 0, stream>>>(degp, x, dinvg, g0, g1);
    k_matvec<<<dim3(GRID_X, NBY), THREADS, 0, stream>>>(dsm, g0, g1, tpart);
    k_head<<<dim3(N / 256, 2), 1024, 0, stream>>>(dinvg, tpart, w1, b1,
                                                  lw1, lb1, lw2, lb2,
                                                  hpart, (float*)d_out);
    k_out<<<1, 64, 0, stream>>>(hpart, w2, b2, w3, b3, wv, bv, (float*)d_out);
}

// Round 9
// 422.578 us; speedup vs baseline: 1.0348x; 1.0215x over previous
//
#include <hip/hip_runtime.h>
#include <math.h>

#define N 8192
#define NV4 (N / 4)             // float4 columns per row
#define THREADS 256
#define RPB 64                  // rows per strip (both passes)
#define NBY (N / RPB)           // 128 strips
#define GRID_X 8                // NV4 / THREADS

typedef float f4 __attribute__((ext_vector_type(4)));

// ws layout (floats) — every region fully overwritten before read (poison-safe),
// no atomics anywhere (replay-safe for rocprof counter groups).
// Cached (non-NT) stores throughout: consumers read L2/L3 (NT stores regressed R2).
//   degp  : [NBY][N]      pass-1 partial column sums             (4 MB)
//   tpart : [NBY][2][N]   pass-2 partial matvec results          (8 MB)
//   dinvg : [N]           rsqrt(deg)
//   g0,g1 : [N]           dinv[r] * x[b][r] per batch
//   hpart : [2][32]       per-(batch, head-block) partial sums of h3
#define DEGP_OFF  0
#define TPART_OFF (NBY * N)
#define DINV_OFF  (TPART_OFF + NBY * 2 * N)
#define G0_OFF    (DINV_OFF + N)
#define G1_OFF    (G0_OFF + N)
#define HPART_OFF (G1_OFF + N)

// Pass 1a: strips 0..NBY/2-1 with NT loads (no L3 allocation). After pass 1,
// L3 retains only the BOTTOM half of DSM (128 MiB + partials fits), so pass 2
// streams top half from HBM and bottom half from L3 concurrently — two BW
// paths aggregated instead of one. Branch-free body (the R7/R8 divergent
// variant never got benched; this splits the halves into two kernels).
__global__ void k_colsum_nt(const float* __restrict__ dsm, float* __restrict__ degp) {
    int chunk = (blockIdx.x + blockIdx.y) & (GRID_X - 1);   // column-phase swizzle
    int c4 = chunk * THREADS + threadIdx.x;
    int r0 = blockIdx.y * RPB;                              // strips 0..63
    const f4* p = (const f4*)dsm + (size_t)r0 * NV4 + c4;
    f4 acc = 0.f;
#pragma unroll 8
    for (int i = 0; i < RPB; ++i)
        acc += __builtin_nontemporal_load(&p[(size_t)i * NV4]);
    ((f4*)(degp + (size_t)blockIdx.y * N))[c4] = acc;
}

// Pass 1b: strips NBY/2..NBY-1 with normal (L3-allocating) loads.
__global__ void k_colsum_c(const float* __restrict__ dsm, float* __restrict__ degp) {
    int by = blockIdx.y + NBY / 2;                          // strips 64..127
    int chunk = (blockIdx.x + by) & (GRID_X - 1);
    int c4 = chunk * THREADS + threadIdx.x;
    int r0 = by * RPB;
    const f4* p = (const f4*)dsm + (size_t)r0 * NV4 + c4;
    f4 acc = 0.f;
#pragma unroll 8
    for (int i = 0; i < RPB; ++i)
        acc += p[(size_t)i * NV4];
    ((f4*)(degp + (size_t)by * N))[c4] = acc;
}

// Tiny: full deg reduction + dinv + pre-scaled per-row gather weights.
// 256 blocks x 256 threads; block owns 32 columns, 8-way strip split.
__global__ void k_dinv(const float* __restrict__ degp, const float* __restrict__ x,
                       float* __restrict__ dinvg, float* __restrict__ g0,
                       float* __restrict__ g1) {
    __shared__ float sred[8][32];
    int c0 = blockIdx.x * 32;
    int cl = threadIdx.x & 31;
    int q  = threadIdx.x >> 5;
    const float* dp = degp + c0 + cl;
    float s = 0.f;
#pragma unroll 8
    for (int j = 0; j < NBY / 8; ++j) s += dp[(size_t)(q * (NBY / 8) + j) * N];
    sred[q][cl] = s;
    __syncthreads();
    if (threadIdx.x < 32) {
        int c = c0 + threadIdx.x;
        float d = 0.f;
#pragma unroll
        for (int q2 = 0; q2 < 8; ++q2) d += sred[q2][threadIdx.x];
        float di = d > 0.f ? rsqrtf(d) : 0.f;
        dinvg[c] = di;
        g0[c] = di * x[c];
        g1[c] = di * x[N + c];
    }
}

// Pass 2: weighted partial matvec over a 64-row strip. Strip order REVERSED
// vs pass 1 (L3/L2-fresh lines first). All 1024 blocks are co-resident
// (4/CU), so the HBM-half and L3-half blocks stream their halves in parallel.
__global__ void k_matvec(const float* __restrict__ dsm, const float* __restrict__ g0,
                         const float* __restrict__ g1, float* __restrict__ tpart) {
    __shared__ float sg0[RPB];
    __shared__ float sg1[RPB];
    int by = NBY - 1 - blockIdx.y;           // reversed strip order
    int r0 = by * RPB;
    if (threadIdx.x < RPB) {
        sg0[threadIdx.x] = g0[r0 + threadIdx.x];
        sg1[threadIdx.x] = g1[r0 + threadIdx.x];
    }
    __syncthreads();
    int chunk = (blockIdx.x + blockIdx.y) & (GRID_X - 1);
    int c4 = chunk * THREADS + threadIdx.x;
    const f4* p = (const f4*)dsm + (size_t)r0 * NV4 + c4;
    f4 a0 = 0.f, a1 = 0.f;
#pragma unroll 8
    for (int i = 0; i < RPB; ++i) {
        f4 v = p[(size_t)i * NV4];
        a0 += v * sg0[i];
        a1 += v * sg1[i];
    }
    ((f4*)(tpart + ((size_t)by * 2 + 0) * N))[c4] = a0;
    ((f4*)(tpart + ((size_t)by * 2 + 1) * N))[c4] = a1;
}

// Head: grid (32, 2), 1024 threads. 4 threads/column split the 128-strip
// tpart reduction (32 strided L3 loads each), LDS combine, scalar MLP chain,
// block-reduce h3 into hpart.
__global__ void k_head(const float* __restrict__ dinvg, const float* __restrict__ tpart,
                       const float* __restrict__ w1, const float* __restrict__ b1,
                       const float* __restrict__ lw1, const float* __restrict__ lb1,
                       const float* __restrict__ lw2, const float* __restrict__ lb2,
                       float* __restrict__ hpart, float* __restrict__ out) {
    __shared__ float sred[4][256];
    __shared__ float swred[4];
    int cl = threadIdx.x & 255;          // column within block
    int q  = threadIdx.x >> 8;           // quarter: 32 strips each
    int c  = blockIdx.x * 256 + cl;
    int b  = blockIdx.y;

    const float* tp = tpart + (size_t)b * N + c + (size_t)(q * 32) * 2 * N;
    float t = 0.f;
#pragma unroll 8
    for (int by = 0; by < 32; ++by) t += tp[(size_t)by * 2 * N];
    sred[q][cl] = t;
    __syncthreads();

    if (threadIdx.x < 256) {
        float tt = sred[0][cl] + sred[1][cl] + sred[2][cl] + sred[3][cl];
        float di = dinvg[c];
        float h = fmaxf(w1[0] * di * tt + b1[0], 0.f);
        h = fmaxf(h * lw1[0] + lb1[0], 0.f);
        h = fmaxf(h * lw2[0] + lb2[0], 0.f);

        // softmax over singleton last axis == 1.0 exactly
        out[(size_t)b * N + c] = 1.0f;

        // reduce h across the 256 finalizer threads (4 full waves)
        float v = h;
        for (int off = 32; off > 0; off >>= 1) v += __shfl_down(v, off);
        int wave = threadIdx.x >> 6;
        if ((threadIdx.x & 63) == 0) swred[wave] = v;
    }
    __syncthreads();
    if (threadIdx.x == 0)
        hpart[b * 32 + blockIdx.x] = swred[0] + swred[1] + swred[2] + swred[3];
}

__global__ void k_out(const float* __restrict__ hpart,
                      const float* __restrict__ w2, const float* __restrict__ b2,
                      const float* __restrict__ w3, const float* __restrict__ b3,
                      const float* __restrict__ wv, const float* __restrict__ bv,
                      float* __restrict__ out) {
    int tid = threadIdx.x;
    float s0 = tid < 32 ? hpart[tid] : 0.f;
    float s1 = tid < 32 ? hpart[32 + tid] : 0.f;
    for (int off = 16; off > 0; off >>= 1) {
        s0 += __shfl_down(s0, off);
        s1 += __shfl_down(s1, off);
    }
    if (tid == 0) {
        float m0 = s0 * (1.0f / (float)N);
        float m1 = s1 * (1.0f / (float)N);
        float a = fmaxf(m0 * w2[0] + b2[0], 0.f);
        a = fmaxf(a * w3[0] + b3[0], 0.f);
        float b = fmaxf(m1 * w2[0] + b2[0], 0.f);
        b = fmaxf(b * w3[0] + b3[0], 0.f);
        float vmax = fmaxf(a, b);
        out[2 * N] = vmax * wv[0] + bv[0];
    }
}

extern "C" void kernel_launch(void* const* d_in, const int* in_sizes, int n_in,
                              void* d_out, int out_size, void* d_ws, size_t ws_size,
                              hipStream_t stream) {
    const float* x   = (const float*)d_in[0];
    const float* dsm = (const float*)d_in[1];
    const float* w1  = (const float*)d_in[2];
    const float* b1  = (const float*)d_in[3];
    const float* lw1 = (const float*)d_in[4];
    const float* lb1 = (const float*)d_in[5];
    const float* lw2 = (const float*)d_in[6];
    const float* lb2 = (const float*)d_in[7];
    const float* w2  = (const float*)d_in[8];
    const float* b2  = (const float*)d_in[9];
    const float* w3  = (const float*)d_in[10];
    const float* b3  = (const float*)d_in[11];
    // d_in[12..13] = wa, ba unused: softmax over a singleton axis == 1.0
    const float* wv  = (const float*)d_in[14];
    const float* bv  = (const float*)d_in[15];

    float* ws    = (float*)d_ws;
    float* degp  = ws + DEGP_OFF;
    float* tpart = ws + TPART_OFF;
    float* dinvg = ws + DINV_OFF;
    float* g0    = ws + G0_OFF;
    float* g1    = ws + G1_OFF;
    float* hpart = ws + HPART_OFF;

    k_colsum_nt<<<dim3(GRID_X, NBY / 2), THREADS, 0, stream>>>(dsm, degp);
    k_colsum_c <<<dim3(GRID_X, NBY / 2), THREADS, 0, stream>>>(dsm, degp);
    k_dinv<<<N / 32, THREADS, 0, stream>>>(degp, x, dinvg, g0, g1);
    k_matvec<<<dim3(GRID_X, NBY), THREADS, 0, stream>>>(dsm, g0, g1, tpart);
    k_head<<<dim3(N / 256, 2), 1024, 0, stream>>>(dinvg, tpart, w1, b1,
                                                  lw1, lb1, lw2, lb2,
                                                  hpart, (float*)d_out);
    k_out<<<1, 64, 0, stream>>>(hpart, w2, b2, w3, b3, wv, bv, (float*)d_out);
}